// Round 5
// baseline (313.982 us; speedup 1.0000x reference)
//
#include <hip/hip_runtime.h>
#include <hip/hip_fp16.h>

#define THREADS 256

typedef int int4v __attribute__((ext_vector_type(4)));

// ws layout:
//   ws[0] (double)  = sum over edges of (1-p_u)(1-p_v) for u!=v
//   ws[1] (double)  = sum over nodes of probs
//   byte offset 256 = fp16 table q[i] = 1 - probs[i]  (N_NODES * 2 bytes)

__device__ __forceinline__ void block_reduce_atomic(float local, double* dst,
                                                    double* sdata) {
    double d = (double)local;
    #pragma unroll
    for (int off = 32; off > 0; off >>= 1)
        d += __shfl_down(d, off, 64);
    int lane = threadIdx.x & 63;
    int wid  = threadIdx.x >> 6;
    if (lane == 0) sdata[wid] = d;
    __syncthreads();
    if (threadIdx.x == 0) {
        double s = 0.0;
        #pragma unroll
        for (int i = 0; i < (THREADS / 64); ++i) s += sdata[i];
        atomicAdd(dst, s);
    }
}

// Build q = 1 - p as fp16 table; fused: also reduce sum(probs).
__global__ void __launch_bounds__(THREADS) build_table_kernel(
        const float* __restrict__ probs,
        __half* __restrict__ qt,
        double* __restrict__ ws,
        long long n_nodes) {
    __shared__ double sdata[THREADS / 64];
    long long n4 = n_nodes >> 2;
    const float4* p4 = (const float4*)probs;
    ushort4* q4 = (ushort4*)qt;
    long long tid = (long long)blockIdx.x * blockDim.x + threadIdx.x;
    long long stride = (long long)gridDim.x * blockDim.x;

    float local = 0.0f;
    for (long long i = tid; i < n4; i += stride) {
        float4 v = p4[i];
        local += (v.x + v.y) + (v.z + v.w);
        ushort4 q;
        q.x = __half_as_ushort(__float2half(1.0f - v.x));
        q.y = __half_as_ushort(__float2half(1.0f - v.y));
        q.z = __half_as_ushort(__float2half(1.0f - v.z));
        q.w = __half_as_ushort(__float2half(1.0f - v.w));
        q4[i] = q;
    }
    for (long long i = (n4 << 2) + tid; i < n_nodes; i += stride) {
        float p = probs[i];
        local += p;
        qt[i] = __float2half(1.0f - p);
    }

    block_reduce_atomic(local, ws + 1, sdata);
}

// 16 edges (32 gathers) per thread, exact cover, all gathers independent and
// issued before any use. No launch_bounds: let the register allocator keep the
// whole batch in flight instead of splitting it to fit 32 VGPRs.
__global__ void edge_sum_kernel(
        const __half* __restrict__ qt,
        const int* __restrict__ row,
        const int* __restrict__ col,
        double* __restrict__ ws,
        long long n_edges) {
    __shared__ double sdata[THREADS / 64];
    long long n4 = n_edges >> 2;   // int4 groups
    long long G4 = n4 >> 2;        // groups per quarter; T = G4 threads
    long long t  = (long long)blockIdx.x * blockDim.x + threadIdx.x;

    const int4v* row4 = (const int4v*)row;
    const int4v* col4 = (const int4v*)col;

    float local = 0.0f;
    if (t < G4) {
        int4v u[4], v[4];
        #pragma unroll
        for (int k = 0; k < 4; ++k) {
            u[k] = __builtin_nontemporal_load(&row4[t + (long long)k * G4]);
            v[k] = __builtin_nontemporal_load(&col4[t + (long long)k * G4]);
        }

        // 32 independent gathers, fully static indexing
        __half a[16], b[16];
        #pragma unroll
        for (int k = 0; k < 4; ++k) {
            a[4 * k + 0] = qt[u[k].x];
            a[4 * k + 1] = qt[u[k].y];
            a[4 * k + 2] = qt[u[k].z];
            a[4 * k + 3] = qt[u[k].w];
            b[4 * k + 0] = qt[v[k].x];
            b[4 * k + 1] = qt[v[k].y];
            b[4 * k + 2] = qt[v[k].z];
            b[4 * k + 3] = qt[v[k].w];
        }

        #pragma unroll
        for (int k = 0; k < 4; ++k) {
            local += (u[k].x != v[k].x)
                         ? __half2float(a[4 * k + 0]) * __half2float(b[4 * k + 0]) : 0.0f;
            local += (u[k].y != v[k].y)
                         ? __half2float(a[4 * k + 1]) * __half2float(b[4 * k + 1]) : 0.0f;
            local += (u[k].z != v[k].z)
                         ? __half2float(a[4 * k + 2]) * __half2float(b[4 * k + 2]) : 0.0f;
            local += (u[k].w != v[k].w)
                         ? __half2float(a[4 * k + 3]) * __half2float(b[4 * k + 3]) : 0.0f;
        }
    }

    // tail: edges past 16*G4 (empty for 32M edges)
    long long covered = G4 << 4;
    long long total_threads = (long long)gridDim.x * blockDim.x;
    for (long long e = covered + t; e < n_edges; e += total_threads) {
        int uu = row[e], vv = col[e];
        float tt = __half2float(qt[uu]) * __half2float(qt[vv]);
        local += (uu != vv) ? tt : 0.0f;
    }

    block_reduce_atomic(local, ws, sdata);
}

__global__ void finalize_kernel(const double* __restrict__ ws,
                                const int* __restrict__ batch,
                                long long n_nodes,
                                const float* __restrict__ pc,
                                float* __restrict__ out) {
    double edge_s = ws[0];
    double prob_s = ws[1];
    double G = (double)(batch[n_nodes - 1] + 1);  // batch is sorted
    double ed = edge_s / G;
    double ew = prob_s / G;
    double loss = (double)pc[0] * ed + ew;
    out[0] = (float)loss;
    out[1] = (float)ew;
    out[2] = (float)ed;
}

extern "C" void kernel_launch(void* const* d_in, const int* in_sizes, int n_in,
                              void* d_out, int out_size, void* d_ws, size_t ws_size,
                              hipStream_t stream) {
    const float* probs = (const float*)d_in[0];
    const int* edge_index = (const int*)d_in[1];   // harness passes integers as int32
    const int* batch = (const int*)d_in[2];
    const float* pc = (const float*)d_in[3];

    long long n_nodes = (long long)in_sizes[0];
    long long n_edges = (long long)in_sizes[1] / 2;
    const int* row = edge_index;
    const int* col = edge_index + n_edges;

    double* ws = (double*)d_ws;
    hipMemsetAsync(ws, 0, 2 * sizeof(double), stream);

    __half* qt = (__half*)((char*)d_ws + 256);
    build_table_kernel<<<512, THREADS, 0, stream>>>(probs, qt, ws, n_nodes);

    long long T = (n_edges >> 2) >> 2;           // 16 edges per thread
    long long blocks = (T + THREADS - 1) / THREADS;
    if (blocks < 1) blocks = 1;
    edge_sum_kernel<<<(int)blocks, THREADS, 0, stream>>>(qt, row, col, ws, n_edges);

    finalize_kernel<<<1, 1, 0, stream>>>(ws, batch, n_nodes, pc, (float*)d_out);
}